// Round 4
// baseline (453.144 us; speedup 1.0000x reference)
//
#include <hip/hip_runtime.h>
#include <cstdint>
#include <cstddef>

// ---------------------------------------------------------------------------
// NN_each_LN_exp: all 33x33 SAME convs on 32x32 maps are dense 1024x1024
// linear operators -> f16 MFMA GEMMs with fused epilogues.
// Row layout r = n*4 + k: the 32x32 MFMA C/D reg-quad holds all 4 colors of
// one (n,o) cell -> sigmoid/mask fusion is lane-local.
// R3: 32x32x16 MFMA, 128x256 block (grid 512 = 2/CU), fully-async staging.
// R4 FIX: kk loop 0..3 (32x32x16 has K=16; BK=64 needs 4 k-steps, not 2 —
// R3 silently dropped half of K).
// ---------------------------------------------------------------------------

typedef _Float16 f16;
typedef __attribute__((ext_vector_type(8))) _Float16 f16x8;
typedef __attribute__((ext_vector_type(16))) float f32x16;

#define NB   4096          // batch
#define PIX  1024          // 32*32
#define MR   (NB * 4)      // color-expanded rows

__device__ __forceinline__ void gld_lds16(const void* g, void* l) {
    // async global->LDS, 16B/lane; LDS dst is wave-uniform base + lane*16
    __builtin_amdgcn_global_load_lds(
        (const __attribute__((address_space(1))) void*)g,
        (__attribute__((address_space(3))) void*)l, 16, 0, 0);
}

// Build the 4 conv matrices (1024x1024 f16): M[o][in] = w[a-i+16][b-j+16]
__global__ void build_mats(const float* __restrict__ we, const float* __restrict__ wn,
                           const float* __restrict__ wn2, const float* __restrict__ wem,
                           f16* __restrict__ Me, f16* __restrict__ Mn,
                           f16* __restrict__ Mn2, f16* __restrict__ Mem) {
    int idx = blockIdx.x * 256 + threadIdx.x;      // over 1024*1024
    int o = idx >> 10, in = idx & 1023;
    int i = o >> 5, j = o & 31, a = in >> 5, b = in & 31;
    int u = a - i + 16, v = b - j + 16;
    bool ok = (u >= 0) && (u < 33) && (v >= 0) && (v < 33);
    int w = u * 33 + v;
    float ve = 0.f, vn = 0.f, vn2 = 0.f, vem = 0.f;
    if (ok) { ve = we[w]; vn = wn[w]; vn2 = wn2[w]; vem = wem[w]; }
    Me[idx]  = (f16)ve;
    Mn[idx]  = (f16)vn;
    Mn2[idx] = (f16)vn2;
    Mem[idx] = (f16)vem;
}

// W1 (100,1024) fp32 -> padded (128,1024) f16
__global__ void build_w1(const float* __restrict__ W1, f16* __restrict__ W1b) {
    int idx = blockIdx.x * 256 + threadIdx.x;      // over 128*1024
    int j = idx >> 10, i = idx & 1023;
    W1b[idx] = (f16)(j < 100 ? W1[j * 1024 + i] : 0.f);
}

// dots (34,32,4096) int32, (v,h,b) -> board[n*1024+p] bytes, LDS transpose
__global__ void build_board(const int* __restrict__ dots, unsigned char* __restrict__ board) {
    __shared__ unsigned char tile[64][68];
    int t = threadIdx.x;
    int bp = blockIdx.x & 15, bn = blockIdx.x >> 4;   // grid 16*64 = 1024
    int p0 = bp * 64, n0 = bn * 64;
    int ln = t & 63, lp = t >> 6;                     // lp 0..3
#pragma unroll
    for (int j = 0; j < 16; j++) {
        int p = lp * 16 + j;
        tile[p][ln] = (unsigned char)dots[(size_t)(p0 + p) * 4096 + n0 + ln];
    }
    __syncthreads();
#pragma unroll
    for (int j = 0; j < 16; j++) {
        int n = lp * 16 + j;
        board[(size_t)(n0 + n) * 1024 + p0 + ln] = tile[ln][n];
    }
}

// ---------------------------------------------------------------------------
// GEMM: C(M x BN-grid) = A(M x 1024) * Mt(N x 1024)^T, f16 in, fp32 acc.
// BM=128, BN=NT*64, BK=64, 256 thr = 4 waves as 2x2 (wave tile 64 x NT*32),
// v_mfma_f32_32x32x16_f16. All tiles staged async with XOR chunk swizzle.
// ASRC: 0 direct f16  1 NC*s (frag-time mul)  2 each(board)  3 notm(board)
//       4 empty(board, M=image-rows)
// MODE: 0 f16-out  2 stage1-fused  3 depth-fused  4 depth-final(feat)
//       5 f32-out+leakyrelu
// ---------------------------------------------------------------------------
template <int MODE, int ASRC, int NT>
__global__ void __launch_bounds__(256, 2) gemm_k(
    const f16* __restrict__ X, const f16* __restrict__ Mt, int ypx, int nx,
    const f16* __restrict__ NCs, const f16* __restrict__ Sin,
    const unsigned char* __restrict__ board, const f16* __restrict__ En,
    float* __restrict__ Lsel, f16* __restrict__ outB, int ldo,
    float* __restrict__ outF) {
    constexpr int BN = NT * 64;
    constexpr int SMB = BN * 128;                  // B tile bytes
    constexpr int SMA = (ASRC == 0) ? 128 * 128
                      : (ASRC == 1) ? (128 * 128 + 32 * 128)
                      : (ASRC == 4) ? 128 * 64
                                    : 32 * 64;
    __shared__ __attribute__((aligned(16))) char smem[SMB + SMA];
    char* smB = smem;
    char* smA = smem + SMB;                        // NC / X / board
    char* smS = smA + 128 * 128;                   // s tile (ASRC 1)

    const int tid = threadIdx.x;
    const int wv = tid >> 6, ln = tid & 63;
    const int wm = wv >> 1, wn_ = wv & 1;
    const int lc = ln & 31, h = ln >> 5;

    // XCD-banded swizzle: i%8 -> XCD; each XCD owns a contiguous y-band,
    // x fastest within the band (A band + B slice stay L2-resident).
    int bi = blockIdx.x;
    int xcd = bi & 7, slot = bi >> 3;
    int bx = slot % nx;
    int by = xcd * ypx + slot / nx;
    const int rtile = by * 128, otile = bx * BN;
    const int img0 = (ASRC == 4) ? rtile : (rtile >> 2);

    f32x16 acc[2][NT];
#pragma unroll
    for (int i = 0; i < 2; i++)
#pragma unroll
        for (int j = 0; j < NT; j++)
#pragma unroll
            for (int v = 0; v < 16; v++) acc[i][j][v] = 0.f;

    for (int kb = 0; kb < 1024; kb += 64) {
        // ---- async staging (XOR-swizzled 16B chunks) ----
#pragma unroll
        for (int s0 = wv * 64; s0 < BN * 8; s0 += 256) {      // B tile
            int slot_ = s0 + ln, row = slot_ >> 3;
            int gcol = (slot_ & 7) ^ (row & 7);
            gld_lds16(Mt + (size_t)(otile + row) * 1024 + kb + gcol * 8,
                      smB + s0 * 16);
        }
        if (ASRC == 0) {
#pragma unroll
            for (int s0 = wv * 64; s0 < 1024; s0 += 256) {
                int slot_ = s0 + ln, row = slot_ >> 3;
                int gcol = (slot_ & 7) ^ (row & 7);
                gld_lds16(X + (size_t)(rtile + row) * 1024 + kb + gcol * 8,
                          smA + s0 * 16);
            }
        } else if (ASRC == 1) {
#pragma unroll
            for (int s0 = wv * 64; s0 < 1024; s0 += 256) {    // NC rows
                int slot_ = s0 + ln, row = slot_ >> 3;
                int gcol = (slot_ & 7) ^ (row & 7);
                gld_lds16(NCs + (size_t)(rtile + row) * 1024 + kb + gcol * 8,
                          smA + s0 * 16);
            }
            {                                                 // s rows (32)
                int slot_ = wv * 64 + ln, row = slot_ >> 3;
                int gcol = (slot_ & 7) ^ (row & 7);
                gld_lds16(Sin + (size_t)(img0 + row) * 1024 + kb + gcol * 8,
                          smS + wv * 64 * 16);
            }
        } else {                                              // board bytes
            constexpr int BSLOTS = (ASRC == 4) ? 512 : 128;   // rows*4 chunks
#pragma unroll
            for (int s0 = wv * 64; s0 < BSLOTS; s0 += 256) {
                int slot_ = s0 + ln, row = slot_ >> 2;
                int gc = (slot_ & 3) ^ (row & 3);
                gld_lds16(board + (size_t)(img0 + row) * 1024 + kb + gc * 16,
                          smA + s0 * 16);
            }
        }
        __syncthreads();

        // ---- compute: 4 kk x (2 m-tiles x NT n-tiles); K=16 per MFMA ----
#pragma unroll
        for (int kk = 0; kk < 4; kk++) {
            const int oct = kk * 2 + h;            // 8-elem k-group, 0..7
            f16x8 af[2], bf[NT];
#pragma unroll
            for (int i = 0; i < 2; i++) {
                int m = wm * 64 + i * 32 + lc;
                if (ASRC == 0) {
                    af[i] = *(const f16x8*)(smA + m * 128 + ((oct) ^ (m & 7)) * 16);
                } else if (ASRC == 1) {
                    f16x8 nc = *(const f16x8*)(smA + m * 128 + ((oct) ^ (m & 7)) * 16);
                    int img = m >> 2;
                    f16x8 sv = *(const f16x8*)(smS + img * 128 + ((oct) ^ (img & 7)) * 16);
                    af[i] = nc * sv;
                } else {
                    int row = (ASRC == 4) ? m : (m >> 2);
                    int k1 = (m & 3) + 1;
                    uint64_t bb = *(const uint64_t*)(smA + row * 64 +
                                   (((oct >> 1)) ^ (row & 3)) * 16 + (oct & 1) * 8);
                    f16x8 v;
#pragma unroll
                    for (int jj = 0; jj < 8; jj++) {
                        int bj = (int)((bb >> (8 * jj)) & 0xff);
                        bool on = (ASRC == 2) ? (bj == k1)
                                : (ASRC == 3) ? (bj != 0 && bj != k1)
                                              : (bj == 0);
                        v[jj] = on ? (f16)1.f : (f16)0.f;
                    }
                    af[i] = v;
                }
            }
#pragma unroll
            for (int j = 0; j < NT; j++) {
                int bn = wn_ * (NT * 32) + j * 32 + lc;
                bf[j] = *(const f16x8*)(smB + bn * 128 + ((oct) ^ (bn & 7)) * 16);
            }
#pragma unroll
            for (int i = 0; i < 2; i++)
#pragma unroll
                for (int j = 0; j < NT; j++)
                    acc[i][j] = __builtin_amdgcn_mfma_f32_32x32x16_f16(
                        af[i], bf[j], acc[i][j], 0, 0, 0);
        }
        __syncthreads();
    }

    // ---- epilogue: C/D layout col=lc, row=8q+4h+(reg&3); reg-quad = 4 colors
#pragma unroll
    for (int i = 0; i < 2; i++) {
        int rb = rtile + wm * 64 + i * 32;
#pragma unroll
        for (int j = 0; j < NT; j++) {
            int o = otile + wn_ * (NT * 32) + j * 32 + lc;
            f32x16 a = acc[i][j];
#pragma unroll
            for (int q = 0; q < 4; q++) {
                int rr = rb + 8 * q + 4 * h;
                if (MODE == 0) {
#pragma unroll
                    for (int v = 0; v < 4; v++)
                        outB[(size_t)(rr + v) * ldo + o] = (f16)a[4 * q + v];
                } else if (MODE == 5) {
#pragma unroll
                    for (int v = 0; v < 4; v++) {
                        float x = a[4 * q + v];
                        outF[(size_t)(rr + v) * ldo + o] = x > 0.f ? x : 0.2f * x;
                    }
                } else {  // 2, 3, 4: board-fused; one color live per cell
                    int n = rr >> 2;
                    size_t no = (size_t)n * PIX + o;
                    int c = board[no];
                    float E = (float)En[no];
                    float asel = (c == 1) ? a[4 * q] : (c == 2) ? a[4 * q + 1]
                               : (c == 3) ? a[4 * q + 2] : a[4 * q + 3];
                    float Lnew;
                    if (MODE == 2) {
                        float ncsel = (float)NCs[(size_t)(4 * n + (c > 0 ? c - 1 : 0)) * PIX + o];
                        Lnew = (c > 0) ? (asel + E - ncsel) : 0.f;
                    } else {
                        Lnew = (c > 0) ? (Lsel[no] + E + asel) : 0.f;
                    }
                    float s = 1.f / (1.f + __expf(-Lnew));
                    if (MODE != 4) Lsel[no] = Lnew;
                    outB[no] = (f16)s;
                }
            }
        }
    }
}

// MLP layers 2+3: x2 = leaky(x1 @ W2^T); out = x2 @ W3^T. 64 batches/block.
__global__ void __launch_bounds__(256) mlp23(const float* __restrict__ X1,
                                             const float* __restrict__ W2,
                                             const float* __restrict__ W3,
                                             float* __restrict__ out) {
    __shared__ float sW2[10000];
    __shared__ float sW3[100];
    __shared__ float red[256];
    int t = threadIdx.x;
    for (int idx = t; idx < 10000; idx += 256) sW2[idx] = W2[idx];
    if (t < 100) sW3[t] = W3[t];
    __syncthreads();
    int nb = t >> 2, q = t & 3;
    int n = blockIdx.x * 64 + nb;
    const float* x1 = X1 + (size_t)n * 128;
    float xr[100];
#pragma unroll
    for (int i = 0; i < 100; i++) xr[i] = x1[i];
    float partial = 0.f;
    for (int jj = 0; jj < 25; jj++) {
        int j = q + jj * 4;
        const float* w2r = sW2 + j * 100;
        float acc2 = 0.f;
#pragma unroll
        for (int i = 0; i < 100; i++) acc2 += w2r[i] * xr[i];
        partial += sW3[j] * (acc2 > 0.f ? acc2 : 0.2f * acc2);
    }
    red[t] = partial;
    __syncthreads();
    if (q == 0) out[n] = red[t] + red[t + 1] + red[t + 2] + red[t + 3];
}

extern "C" void kernel_launch(void* const* d_in, const int* in_sizes, int n_in,
                              void* d_out, int out_size, void* d_ws, size_t ws_size,
                              hipStream_t stream) {
    (void)in_sizes; (void)n_in; (void)out_size; (void)ws_size;
    const int*   dots   = (const int*)d_in[0];
    const float* w_each = (const float*)d_in[1];
    const float* w_not  = (const float*)d_in[2];
    const float* w_not2 = (const float*)d_in[3];
    const float* w_emp  = (const float*)d_in[4];
    const float* W1 = (const float*)d_in[5];
    const float* W2 = (const float*)d_in[6];
    const float* W3 = (const float*)d_in[7];
    float* out = (float*)d_out;

    char* ws = (char*)d_ws;
    size_t off = 0;
    auto alloc = [&](size_t bytes) -> char* {
        char* p = ws + off;
        off += (bytes + 255) & ~(size_t)255;
        return p;
    };
    f16* Me   = (f16*)alloc((size_t)PIX * PIX * 2);
    f16* Mn   = (f16*)alloc((size_t)PIX * PIX * 2);
    f16* Mn2  = (f16*)alloc((size_t)PIX * PIX * 2);
    f16* Mem  = (f16*)alloc((size_t)PIX * PIX * 2);
    f16* W1b  = (f16*)alloc((size_t)128 * PIX * 2);
    unsigned char* board = (unsigned char*)alloc((size_t)NB * PIX);
    f16*   NC   = (f16*)alloc((size_t)MR * PIX * 2);
    f16*   En   = (f16*)alloc((size_t)NB * PIX * 2);
    f16*   Sa   = (f16*)alloc((size_t)NB * PIX * 2);
    f16*   Sb   = (f16*)alloc((size_t)NB * PIX * 2);
    f16*   feat = (f16*)alloc((size_t)NB * PIX * 2);
    float* Lsel = (float*)alloc((size_t)NB * PIX * 4);
    float* X1   = (float*)alloc((size_t)NB * 128 * 4);

    build_mats<<<4096, 256, 0, stream>>>(w_each, w_not, w_not2, w_emp, Me, Mn, Mn2, Mem);
    build_w1<<<512, 256, 0, stream>>>(W1, W1b);
    build_board<<<1024, 256, 0, stream>>>(dots, board);

    dim3 blk(256);
    // NC[4n+k] = conv(notm_k, w_not): A one-hot from board, out f16
    gemm_k<0, 3, 4><<<512, blk, 0, stream>>>(nullptr, Mn, 16, 4, nullptr, nullptr,
                                             board, nullptr, nullptr, NC, PIX, nullptr);
    // En[n] = conv(empty, w_empty): out f16
    gemm_k<0, 4, 4><<<128, blk, 0, stream>>>(nullptr, Mem, 4, 4, nullptr, nullptr,
                                             board, nullptr, nullptr, En, PIX, nullptr);
    // stage1: A = conv(each, w_each); fused L0/sigmoid -> s
    gemm_k<2, 2, 4><<<512, blk, 0, stream>>>(nullptr, Me, 16, 4, NC, nullptr,
                                             board, En, Lsel, Sa, 0, nullptr);
    // depth 1..3: C = conv(NC*s, w_not2); fused L/sigmoid -> s'
    gemm_k<3, 1, 4><<<512, blk, 0, stream>>>(nullptr, Mn2, 16, 4, NC, Sa,
                                             board, En, Lsel, Sb, 0, nullptr);
    gemm_k<3, 1, 4><<<512, blk, 0, stream>>>(nullptr, Mn2, 16, 4, NC, Sb,
                                             board, En, Lsel, Sa, 0, nullptr);
    gemm_k<3, 1, 4><<<512, blk, 0, stream>>>(nullptr, Mn2, 16, 4, NC, Sa,
                                             board, En, Lsel, Sb, 0, nullptr);
    // depth 4: writes feat = sigmoid only
    gemm_k<4, 1, 4><<<512, blk, 0, stream>>>(nullptr, Mn2, 16, 4, NC, Sb,
                                             board, En, Lsel, feat, 0, nullptr);
    // MLP layer 1 (N padded to 128) with fused leaky relu
    gemm_k<5, 0, 2><<<32, blk, 0, stream>>>(feat, W1b, 4, 1, nullptr, nullptr,
                                            nullptr, nullptr, nullptr, nullptr, 128, X1);
    mlp23<<<64, blk, 0, stream>>>(X1, W2, W3, out);
}

// Round 5
// 433.084 us; speedup vs baseline: 1.0463x; 1.0463x over previous
//
#include <hip/hip_runtime.h>
#include <cstdint>
#include <cstddef>

// ---------------------------------------------------------------------------
// NN_each_LN_exp: 33x33 SAME convs on 32x32 maps = dense 1024x1024 linear
// operators -> f16 MFMA GEMMs with fused epilogues. Row layout r = n*4+k:
// the 16x16x32 MFMA acc quad (rbase+lq*4 .. +3) holds all 4 colors of one
// (n,o) cell -> sigmoid/mask fusion lane-local.
// R5: back to 16x16x32 frags (R2-verified 0 bank conflicts), async staging,
// 4 blocks/CU; NC+En+stage1 fused into one dispatch via the identity
// conv_wn(notm_c) = t_n - conv_wn(empty) - conv_wn(each_c)  =>
// L0 = conv_{we+wn}(each_c) + conv_{wem+wn}(empty) - t_n   (K-ext GEMM).
// ---------------------------------------------------------------------------

typedef _Float16 f16;
typedef __attribute__((ext_vector_type(8))) _Float16 f16x8;
typedef __attribute__((ext_vector_type(4))) float f32x4;

#define NB   4096
#define PIX  1024
#define MR   (NB * 4)

__device__ __forceinline__ void gld_lds16(const void* g, void* l) {
    __builtin_amdgcn_global_load_lds(
        (const __attribute__((address_space(1))) void*)g,
        (__attribute__((address_space(3))) void*)l, 16, 0, 0);
}

// Conv matrices: Mn, Mn2, Mem (1024x1024) and Bst (1024x2048 = [we+wn | wem+wn])
__global__ void build_mats(const float* __restrict__ we, const float* __restrict__ wn,
                           const float* __restrict__ wn2, const float* __restrict__ wem,
                           f16* __restrict__ Mn, f16* __restrict__ Mn2,
                           f16* __restrict__ Mem, f16* __restrict__ Bst) {
    int idx = blockIdx.x * 256 + threadIdx.x;      // over 1024*1024
    int o = idx >> 10, in = idx & 1023;
    int i = o >> 5, j = o & 31, a = in >> 5, b = in & 31;
    int u = a - i + 16, v = b - j + 16;
    bool ok = (u >= 0) && (u < 33) && (v >= 0) && (v < 33);
    int w = u * 33 + v;
    float ve = 0.f, vn = 0.f, vn2 = 0.f, vem = 0.f;
    if (ok) { ve = we[w]; vn = wn[w]; vn2 = wn2[w]; vem = wem[w]; }
    Mn[idx]  = (f16)vn;
    Mn2[idx] = (f16)vn2;
    Mem[idx] = (f16)vem;
    Bst[(size_t)o * 2048 + in]        = (f16)(ve + vn);
    Bst[(size_t)o * 2048 + 1024 + in] = (f16)(vem + vn);
}

// t_n[o] = sum_j Mn[o][j]
__global__ void tn_build(const f16* __restrict__ Mn, float* __restrict__ tn) {
    int o = blockIdx.x * 256 + threadIdx.x;
    float s = 0.f;
    for (int j = 0; j < 128; j++) {
        f16x8 v = *(const f16x8*)(Mn + (size_t)o * 1024 + j * 8);
#pragma unroll
        for (int e = 0; e < 8; e++) s += (float)v[e];
    }
    tn[o] = s;
}

// W1 (100,1024) fp32 -> padded (128,1024) f16
__global__ void build_w1(const float* __restrict__ W1, f16* __restrict__ W1b) {
    int idx = blockIdx.x * 256 + threadIdx.x;
    int j = idx >> 10, i = idx & 1023;
    W1b[idx] = (f16)(j < 100 ? W1[j * 1024 + i] : 0.f);
}

// dots (34,32,4096) int32, (v,h,b) -> board[n*1024+p] bytes, LDS transpose
__global__ void build_board(const int* __restrict__ dots, unsigned char* __restrict__ board) {
    __shared__ unsigned char tile[64][68];
    int t = threadIdx.x;
    int bp = blockIdx.x & 15, bn = blockIdx.x >> 4;
    int p0 = bp * 64, n0 = bn * 64;
    int ln = t & 63, lp = t >> 6;
#pragma unroll
    for (int j = 0; j < 16; j++) {
        int p = lp * 16 + j;
        tile[p][ln] = (unsigned char)dots[(size_t)(p0 + p) * 4096 + n0 + ln];
    }
    __syncthreads();
#pragma unroll
    for (int j = 0; j < 16; j++) {
        int n = lp * 16 + j;
        board[(size_t)(n0 + n) * 1024 + p0 + ln] = tile[ln][n];
    }
}

// ---------------------------------------------------------------------------
// Core GEMM body: BM=BN=128, BK=64, 4 waves as 2x2, 16x16x32 MFMA (R2 frag
// layout, conflict-free). XOR-swizzled 16B chunks; board tiles swizzled on
// 16B granules within 64B rows.
// ASRC: 0 direct f16  1 NC*s  3 notm(board)  4 empty(board)  5 [each|empty] K-ext
// MODE: 0 f16-out  2 stage1 (acc - tn)  3 depth  4 depth-final  5 f32 leaky
// smem layout: [0,16K) B tile; [16K,..) A (f16 rows / board bytes); ASRC1:
// [32K,36K) s tile.
// ---------------------------------------------------------------------------
template <int MODE, int ASRC>
__device__ __forceinline__ void run_gemm(
    int bjob, int ypx, int nx, char* smem,
    const f16* __restrict__ X, const f16* __restrict__ B, int K,
    const unsigned char* __restrict__ board, const f16* __restrict__ NCs,
    const f16* __restrict__ Sin, const f16* __restrict__ En,
    const float* __restrict__ tn, float* __restrict__ Lsel,
    f16* __restrict__ outB, int ldo, float* __restrict__ outF) {
    char* smB = smem;
    char* smA = smem + 16384;
    char* smS = smem + 32768;                      // ASRC1 only

    const int tid = threadIdx.x;
    const int wv = tid >> 6, ln = tid & 63;
    const int wm = wv >> 1, wn_ = wv & 1;
    const int lr = ln & 15, lq = ln >> 4;

    int xcd = bjob & 7, slot = bjob >> 3;
    int bx = slot % nx;
    int by = xcd * ypx + slot / nx;
    const int rtile = by * 128, otile = bx * 128;
    const int img0 = (ASRC == 4) ? rtile : (rtile >> 2);   // board/s map base

    const f32x4 fz = {0.f, 0.f, 0.f, 0.f};
    f32x4 acc[4][4];
#pragma unroll
    for (int i = 0; i < 4; i++)
#pragma unroll
        for (int j = 0; j < 4; j++) acc[i][j] = fz;

    for (int kb = 0; kb < K; kb += 64) {
        // ---- async staging ----
#pragma unroll
        for (int t = 0; t < 4; t++) {              // B: 1024 chunk slots
            int c = t * 256 + wv * 64 + ln;
            int row = c >> 3, gcol = (c & 7) ^ (row & 7);
            gld_lds16(B + (size_t)(otile + row) * K + kb + gcol * 8, smB + c * 16);
        }
        if (ASRC == 0) {
#pragma unroll
            for (int t = 0; t < 4; t++) {
                int c = t * 256 + wv * 64 + ln;
                int row = c >> 3, gcol = (c & 7) ^ (row & 7);
                gld_lds16(X + (size_t)(rtile + row) * K + kb + gcol * 8, smA + c * 16);
            }
        } else if (ASRC == 1) {
#pragma unroll
            for (int t = 0; t < 4; t++) {          // NC rows
                int c = t * 256 + wv * 64 + ln;
                int row = c >> 3, gcol = (c & 7) ^ (row & 7);
                gld_lds16(NCs + (size_t)(rtile + row) * 1024 + kb + gcol * 8, smA + c * 16);
            }
            {                                      // s rows: 256 slots
                int c = wv * 64 + ln;
                int row = c >> 3, gcol = (c & 7) ^ (row & 7);
                gld_lds16(Sin + (size_t)(img0 + row) * 1024 + kb + gcol * 8, smS + c * 16);
            }
        } else if (ASRC == 4) {                    // board: 128 maps = 512 slots
            int cb = kb;
#pragma unroll
            for (int t = 0; t < 2; t++) {
                int c = t * 256 + wv * 64 + ln;
                int row = c >> 2, g = (c & 3) ^ (row & 3);
                gld_lds16(board + (size_t)(img0 + row) * 1024 + cb + g * 16, smA + c * 16);
            }
        } else {                                   // ASRC 3/5: 32 maps = 128 slots
            int cb = (ASRC == 5) ? (kb & 1023) : kb;
            if (wv < 2) {
                int c = wv * 64 + ln;
                int row = c >> 2, g = (c & 3) ^ (row & 3);
                gld_lds16(board + (size_t)(img0 + row) * 1024 + cb + g * 16, smA + c * 16);
            }
        }
        __syncthreads();

        // ---- compute: 2 kk, oct = kk*4+lq in 0..7 ----
#pragma unroll
        for (int kk = 0; kk < 2; kk++) {
            const int oct = kk * 4 + lq;
            f16x8 af[4], bfr[4];
#pragma unroll
            for (int i = 0; i < 4; i++) {
                int rrow = wm * 64 + i * 16 + lr;
                if (ASRC == 0) {
                    af[i] = *(const f16x8*)(smA + rrow * 128 + (oct ^ (rrow & 7)) * 16);
                } else if (ASRC == 1) {
                    f16x8 nc = *(const f16x8*)(smA + rrow * 128 + (oct ^ (rrow & 7)) * 16);
                    int img = rrow >> 2;
                    f16x8 sv = *(const f16x8*)(smS + img * 128 + (oct ^ (img & 7)) * 16);
                    af[i] = nc * sv;
                } else {
                    int m = (ASRC == 4) ? rrow : (rrow >> 2);
                    int k1 = (rrow & 3) + 1;
                    uint64_t bb = *(const uint64_t*)(smA + m * 64 +
                                    (((oct >> 1)) ^ (m & 3)) * 16 + (oct & 1) * 8);
                    bool ext = (ASRC == 5) && (kb >= 1024);
                    f16x8 v;
#pragma unroll
                    for (int jj = 0; jj < 8; jj++) {
                        int bj = (int)((bb >> (8 * jj)) & 0xff);
                        bool on = (ASRC == 4) ? (bj == 0)
                                : (ASRC == 3) ? (bj != 0 && bj != k1)
                                : ext          ? (bj == 0)
                                               : (bj == k1);
                        v[jj] = on ? (f16)1.f : (f16)0.f;
                    }
                    af[i] = v;
                }
            }
#pragma unroll
            for (int j = 0; j < 4; j++) {
                int brow = wn_ * 64 + j * 16 + lr;
                bfr[j] = *(const f16x8*)(smB + brow * 128 + (oct ^ (brow & 7)) * 16);
            }
#pragma unroll
            for (int i = 0; i < 4; i++)
#pragma unroll
                for (int j = 0; j < 4; j++)
                    acc[i][j] = __builtin_amdgcn_mfma_f32_16x16x32_f16(
                        af[i], bfr[j], acc[i][j], 0, 0, 0);
        }
        __syncthreads();
    }

    // ---- epilogue: lane holds rows rbase..rbase+3 (= one cell's 4 colors) ----
#pragma unroll
    for (int i = 0; i < 4; i++) {
        int rbase = rtile + wm * 64 + i * 16 + lq * 4;
#pragma unroll
        for (int j = 0; j < 4; j++) {
            int o = otile + wn_ * 64 + j * 16 + lr;
            f32x4 a = acc[i][j];
            if (MODE == 0) {
#pragma unroll
                for (int v = 0; v < 4; v++)
                    outB[(size_t)(rbase + v) * ldo + o] = (f16)a[v];
            } else if (MODE == 5) {
#pragma unroll
                for (int v = 0; v < 4; v++) {
                    float x = a[v];
                    outF[(size_t)(rbase + v) * ldo + o] = x > 0.f ? x : 0.2f * x;
                }
            } else {
                int n = rbase >> 2;
                size_t no = (size_t)n * PIX + o;
                int c = board[no];
                float asel = (c == 1) ? a[0] : (c == 2) ? a[1] : (c == 3) ? a[2] : a[3];
                float Lnew;
                if (MODE == 2) {
                    Lnew = (c > 0) ? (asel - tn[o]) : 0.f;       // acc already has E-term
                } else {
                    float E = (float)En[no];
                    Lnew = (c > 0) ? (Lsel[no] + E + asel) : 0.f;
                }
                float s = 1.f / (1.f + __expf(-Lnew));
                if (MODE != 4) Lsel[no] = Lnew;
                outB[no] = (f16)s;
            }
        }
    }
}

// Fused phase A: blocks [0,1024) stage1 (K=2048), [1024,2048) NC, [2048,2304) En
__global__ void __launch_bounds__(256, 4) gemm_fa(
    const f16* __restrict__ Bst, const f16* __restrict__ Mn,
    const f16* __restrict__ Mem, const unsigned char* __restrict__ board,
    const float* __restrict__ tn, float* __restrict__ Lsel,
    f16* __restrict__ Sa, f16* __restrict__ NC, f16* __restrict__ En) {
    __shared__ __attribute__((aligned(16))) char smem[24576];
    int bi = blockIdx.x;
    if (bi < 1024) {
        run_gemm<2, 5>(bi, 16, 8, smem, nullptr, Bst, 2048, board, nullptr,
                       nullptr, nullptr, tn, Lsel, Sa, 0, nullptr);
    } else if (bi < 2048) {
        run_gemm<0, 3>(bi - 1024, 16, 8, smem, nullptr, Mn, 1024, board, nullptr,
                       nullptr, nullptr, nullptr, nullptr, NC, PIX, nullptr);
    } else {
        run_gemm<0, 4>(bi - 2048, 4, 8, smem, nullptr, Mem, 1024, board, nullptr,
                       nullptr, nullptr, nullptr, nullptr, En, PIX, nullptr);
    }
}

// Depth GEMM (A = NC*s), MODE 3 (store s+L) or 4 (store feat)
template <int MODE>
__global__ void __launch_bounds__(256, 4) gemm_depth(
    const f16* __restrict__ Mn2, const unsigned char* __restrict__ board,
    const f16* __restrict__ NCs, const f16* __restrict__ Sin,
    const f16* __restrict__ En, float* __restrict__ Lsel,
    f16* __restrict__ outB) {
    __shared__ __attribute__((aligned(16))) char smem[36864];
    run_gemm<MODE, 1>(blockIdx.x, 16, 8, smem, nullptr, Mn2, 1024, board, NCs,
                      Sin, En, nullptr, Lsel, outB, 0, nullptr);
}

// MLP layer 1: X1 = leaky(feat @ W1b^T), N=128
__global__ void __launch_bounds__(256, 4) gemm_mlp(
    const f16* __restrict__ feat, const f16* __restrict__ W1b,
    float* __restrict__ X1) {
    __shared__ __attribute__((aligned(16))) char smem[32768];
    run_gemm<5, 0>(blockIdx.x, 4, 1, smem, feat, W1b, 1024, nullptr, nullptr,
                   nullptr, nullptr, nullptr, nullptr, nullptr, 128, X1);
}

// MLP layers 2+3
__global__ void __launch_bounds__(256) mlp23(const float* __restrict__ X1,
                                             const float* __restrict__ W2,
                                             const float* __restrict__ W3,
                                             float* __restrict__ out) {
    __shared__ float sW2[10000];
    __shared__ float sW3[100];
    __shared__ float red[256];
    int t = threadIdx.x;
    for (int idx = t; idx < 10000; idx += 256) sW2[idx] = W2[idx];
    if (t < 100) sW3[t] = W3[t];
    __syncthreads();
    int nb = t >> 2, q = t & 3;
    int n = blockIdx.x * 64 + nb;
    const float* x1 = X1 + (size_t)n * 128;
    float xr[100];
#pragma unroll
    for (int i = 0; i < 100; i++) xr[i] = x1[i];
    float partial = 0.f;
    for (int jj = 0; jj < 25; jj++) {
        int j = q + jj * 4;
        const float* w2r = sW2 + j * 100;
        float acc2 = 0.f;
#pragma unroll
        for (int i = 0; i < 100; i++) acc2 += w2r[i] * xr[i];
        partial += sW3[j] * (acc2 > 0.f ? acc2 : 0.2f * acc2);
    }
    red[t] = partial;
    __syncthreads();
    if (q == 0) out[n] = red[t] + red[t + 1] + red[t + 2] + red[t + 3];
}

extern "C" void kernel_launch(void* const* d_in, const int* in_sizes, int n_in,
                              void* d_out, int out_size, void* d_ws, size_t ws_size,
                              hipStream_t stream) {
    (void)in_sizes; (void)n_in; (void)out_size; (void)ws_size;
    const int*   dots   = (const int*)d_in[0];
    const float* w_each = (const float*)d_in[1];
    const float* w_not  = (const float*)d_in[2];
    const float* w_not2 = (const float*)d_in[3];
    const float* w_emp  = (const float*)d_in[4];
    const float* W1 = (const float*)d_in[5];
    const float* W2 = (const float*)d_in[6];
    const float* W3 = (const float*)d_in[7];
    float* out = (float*)d_out;

    char* ws = (char*)d_ws;
    size_t off = 0;
    auto alloc = [&](size_t bytes) -> char* {
        char* p = ws + off;
        off += (bytes + 255) & ~(size_t)255;
        return p;
    };
    f16* Mn   = (f16*)alloc((size_t)PIX * PIX * 2);
    f16* Mn2  = (f16*)alloc((size_t)PIX * PIX * 2);
    f16* Mem  = (f16*)alloc((size_t)PIX * PIX * 2);
    f16* Bst  = (f16*)alloc((size_t)PIX * 2048 * 2);
    f16* W1b  = (f16*)alloc((size_t)128 * PIX * 2);
    unsigned char* board = (unsigned char*)alloc((size_t)NB * PIX);
    f16*   NC   = (f16*)alloc((size_t)MR * PIX * 2);
    f16*   En   = (f16*)alloc((size_t)NB * PIX * 2);
    f16*   Sa   = (f16*)alloc((size_t)NB * PIX * 2);
    f16*   Sb   = (f16*)alloc((size_t)NB * PIX * 2);
    f16*   feat = (f16*)alloc((size_t)NB * PIX * 2);
    float* Lsel = (float*)alloc((size_t)NB * PIX * 4);
    float* tn   = (float*)alloc((size_t)PIX * 4);
    float* X1   = (float*)alloc((size_t)NB * 128 * 4);

    build_mats<<<4096, 256, 0, stream>>>(w_each, w_not, w_not2, w_emp, Mn, Mn2, Mem, Bst);
    tn_build<<<4, 256, 0, stream>>>(Mn, tn);
    build_w1<<<512, 256, 0, stream>>>(W1, W1b);
    build_board<<<1024, 256, 0, stream>>>(dots, board);

    dim3 blk(256);
    // Phase A: stage1 (K-ext, no NC dependency) + NC + En in one dispatch
    gemm_fa<<<2304, blk, 0, stream>>>(Bst, Mn, Mem, board, tn, Lsel, Sa, NC, En);
    // depth 1..3: C = conv(NC*s, w_not2); fused L/sigmoid -> s'
    gemm_depth<3><<<1024, blk, 0, stream>>>(Mn2, board, NC, Sa, En, Lsel, Sb);
    gemm_depth<3><<<1024, blk, 0, stream>>>(Mn2, board, NC, Sb, En, Lsel, Sa);
    gemm_depth<3><<<1024, blk, 0, stream>>>(Mn2, board, NC, Sa, En, Lsel, Sb);
    // depth 4: feat = sigmoid only
    gemm_depth<4><<<1024, blk, 0, stream>>>(Mn2, board, NC, Sb, En, Lsel, feat);
    // MLP layer 1 + fused leaky
    gemm_mlp<<<32, blk, 0, stream>>>(feat, W1b, X1);
    mlp23<<<64, blk, 0, stream>>>(X1, W2, W3, out);
}